// Round 2
// baseline (2859.576 us; speedup 1.0000x reference)
//
#include <hip/hip_runtime.h>

#define NN 2048
#define BB 8
#define NITER 50
#define RPB 16                  // rows per block in fused kernel
#define CHUNKS (NN / RPB)       // 128

__device__ __forceinline__ float eps_f()      { return 0.01f; }
__device__ __forceinline__ float inv_eps_f()  { return 100.0f; }
// 0.01f * (-logf(2048.f)) = -0.0762461898616f
__device__ __forceinline__ float eps_logmu_f(){ return -0.0762461898616f; }

// combine two (max, sum-of-exp-relative-to-max) pairs in x-space
// (LSE argument is x * 100, so exponent deltas are scaled by INV_EPS)
__device__ __forceinline__ void lse_combine(float& m, float& s, float om, float os) {
    float M = fmaxf(m, om);
    s = s * __expf((m - M) * inv_eps_f()) + os * __expf((om - M) * inv_eps_f());
    m = M;
}

// ---------------- init: zero u, v ----------------
__global__ __launch_bounds__(256) void k_init(float* __restrict__ u, float* __restrict__ v) {
    int idx = blockIdx.x * 256 + threadIdx.x;
    if (idx < BB * NN) { u[idx] = 0.0f; v[idx] = 0.0f; }
}

// ---------------- fused u update + v partials: ONE pass over c ----------------
// Per block: RPB rows of one batch. For each row:
//   1) u[b,i] = eps*log_mu - max_j(c+v_old) - eps*log(sum_j exp((c+v_old-max)*100))
//      (block-wide LSE reduction; row held in registers)
//   2) accumulate exp((c_ij + u_new_i)*100) into per-thread per-column running (m,s)
//      (the v_j term cancels inside the v update, so columns only need c+u_new)
// At the end, write per-column partial (m,s) for this row-chunk.
__global__ __launch_bounds__(256) void k_uv(const float* __restrict__ c,
                                            const float* __restrict__ v,
                                            float* __restrict__ u,
                                            float* __restrict__ pm,
                                            float* __restrict__ ps) {
    int chunk = blockIdx.x;
    int b     = blockIdx.y;
    int t     = threadIdx.x;
    int wid   = t >> 6;

    const float4* vb = (const float4*)(v + (size_t)b * NN);
    float4 v0 = vb[t];
    float4 v1 = vb[t + 256];

    float mc[8], sc[8];
#pragma unroll
    for (int k = 0; k < 8; ++k) { mc[k] = -INFINITY; sc[k] = 0.0f; }

    __shared__ float sm[4], ss[4], su;

    int i0 = chunk * RPB;
    const float* cbase = c + ((size_t)b * NN + i0) * NN;

    float4 c0 = ((const float4*)cbase)[t];
    float4 c1 = ((const float4*)cbase)[t + 256];

    for (int r = 0; r < RPB; ++r) {
        // prefetch next row while we reduce the current one
        // (clamped index + initialized regs: no UB on the final iteration)
        int rn = (r + 1 < RPB) ? (r + 1) : r;
        const float* nb = cbase + (size_t)rn * NN;
        float4 n0 = ((const float4*)nb)[t];
        float4 n1 = ((const float4*)nb)[t + 256];

        // ---- row LSE over j of (c + v_old) ----
        float x0 = c0.x + v0.x, x1 = c0.y + v0.y, x2 = c0.z + v0.z, x3 = c0.w + v0.w;
        float x4 = c1.x + v1.x, x5 = c1.y + v1.y, x6 = c1.z + v1.z, x7 = c1.w + v1.w;
        float m = fmaxf(fmaxf(fmaxf(x0, x1), fmaxf(x2, x3)),
                        fmaxf(fmaxf(x4, x5), fmaxf(x6, x7)));
        float s = __expf((x0 - m) * inv_eps_f()) + __expf((x1 - m) * inv_eps_f())
                + __expf((x2 - m) * inv_eps_f()) + __expf((x3 - m) * inv_eps_f())
                + __expf((x4 - m) * inv_eps_f()) + __expf((x5 - m) * inv_eps_f())
                + __expf((x6 - m) * inv_eps_f()) + __expf((x7 - m) * inv_eps_f());
#pragma unroll
        for (int off = 32; off; off >>= 1) {
            float om = __shfl_xor(m, off, 64);
            float os = __shfl_xor(s, off, 64);
            lse_combine(m, s, om, os);
        }
        if ((t & 63) == 0) { sm[wid] = m; ss[wid] = s; }
        __syncthreads();
        if (t == 0) {
            float M = sm[0], S = ss[0];
#pragma unroll
            for (int w = 1; w < 4; ++w) lse_combine(M, S, sm[w], ss[w]);
            float ui = eps_logmu_f() - M - eps_f() * __logf(S);
            su = ui;
            u[(size_t)b * NN + i0 + r] = ui;
        }
        __syncthreads();
        float ui = su;

        // ---- column accumulate: y = c + u_new_i ----
        float yv[8] = { c0.x + ui, c0.y + ui, c0.z + ui, c0.w + ui,
                        c1.x + ui, c1.y + ui, c1.z + ui, c1.w + ui };
#pragma unroll
        for (int k = 0; k < 8; ++k) {
            float M = fmaxf(mc[k], yv[k]);
            sc[k] = sc[k] * __expf((mc[k] - M) * inv_eps_f())
                  + __expf((yv[k] - M) * inv_eps_f());
            mc[k] = M;
        }

        c0 = n0; c1 = n1;
    }

    size_t o = (size_t)(b * CHUNKS + chunk) * NN;
    ((float4*)(pm + o))[t]       = make_float4(mc[0], mc[1], mc[2], mc[3]);
    ((float4*)(pm + o))[t + 256] = make_float4(mc[4], mc[5], mc[6], mc[7]);
    ((float4*)(ps + o))[t]       = make_float4(sc[0], sc[1], sc[2], sc[3]);
    ((float4*)(ps + o))[t + 256] = make_float4(sc[4], sc[5], sc[6], sc[7]);
}

// ---------------- v update, phase 2: combine partials ----------------
// Each block: 64 consecutive columns of one batch. 4 waves each combine a
// strided quarter of the CHUNKS partials (coalesced 256B loads), then merge
// across waves in LDS.
__global__ __launch_bounds__(256) void k_v_combine(const float* __restrict__ pm,
                                                   const float* __restrict__ ps,
                                                   float* __restrict__ v) {
    int blk  = blockIdx.x;
    int b    = blk / (NN / 64);
    int jb   = (blk % (NN / 64)) * 64;
    int t    = threadIdx.x;
    int wid  = t >> 6;
    int lane = t & 63;
    int j    = jb + lane;

    float m = -INFINITY, s = 0.0f;
    size_t base = (size_t)b * CHUNKS * NN + j;
    for (int r = wid; r < CHUNKS; r += 4) {
        size_t o = base + (size_t)r * NN;
        lse_combine(m, s, pm[o], ps[o]);
    }

    __shared__ float lm[4][64], ls[4][64];
    lm[wid][lane] = m; ls[wid][lane] = s;
    __syncthreads();
    if (t < 64) {
        m = lm[0][lane]; s = ls[0][lane];
#pragma unroll
        for (int w = 1; w < 4; ++w) lse_combine(m, s, lm[w][lane], ls[w][lane]);
        float val = eps_logmu_f() - m - eps_f() * __logf(s);
        if (val > 9e8f) val = 0.0f;   // reference's huge-value clamp (never fires in practice)
        v[(size_t)b * NN + j] = val;
    }
}

// ---------------- finalize: pi = exp((c+u+v)*100), negc = -c ----------------
__global__ __launch_bounds__(256) void k_final(const float* __restrict__ c,
                                               const float* __restrict__ u,
                                               const float* __restrict__ v,
                                               float* __restrict__ pi,
                                               float* __restrict__ negc) {
    unsigned q = blockIdx.x * 256 + threadIdx.x;     // float4 index
    unsigned e = q * 4;                               // element index
    unsigned b = e >> 22;                             // / (NN*NN)
    unsigned rem = e & (NN * NN - 1);
    unsigned i = rem >> 11;
    unsigned j = rem & (NN - 1);

    float4 cc = ((const float4*)c)[q];
    float ui = u[b * NN + i];
    const float* vp = v + b * NN + j;
    float4 vv = *(const float4*)vp;

    float4 p;
    p.x = __expf((cc.x + ui + vv.x) * inv_eps_f());
    p.y = __expf((cc.y + ui + vv.y) * inv_eps_f());
    p.z = __expf((cc.z + ui + vv.z) * inv_eps_f());
    p.w = __expf((cc.w + ui + vv.w) * inv_eps_f());
    ((float4*)pi)[q] = p;

    float4 nc = { -cc.x, -cc.y, -cc.z, -cc.w };
    ((float4*)negc)[q] = nc;
}

// ---------------- copy u, v to output ----------------
__global__ __launch_bounds__(256) void k_uv_out(const float* __restrict__ u,
                                                const float* __restrict__ v,
                                                float* __restrict__ ou,
                                                float* __restrict__ ov) {
    int idx = blockIdx.x * 256 + threadIdx.x;
    if (idx < BB * NN) { ou[idx] = u[idx]; ov[idx] = v[idx]; }
}

extern "C" void kernel_launch(void* const* d_in, const int* in_sizes, int n_in,
                              void* d_out, int out_size, void* d_ws, size_t ws_size,
                              hipStream_t stream) {
    const float* c = (const float*)d_in[0];
    float* out  = (float*)d_out;
    float* pi   = out;
    float* negc = out + (size_t)BB * NN * NN;
    float* ou   = out + 2 * (size_t)BB * NN * NN;
    float* ov   = ou + BB * NN;

    float* ws = (float*)d_ws;
    float* u  = ws;
    float* v  = ws + BB * NN;
    // Partials (2 x 8.4 MB) live in the negc output region during iterations;
    // negc itself is written only afterwards by k_final.
    float* pm = negc;
    float* ps = negc + (size_t)BB * CHUNKS * NN;

    k_init<<<(BB * NN) / 256, 256, 0, stream>>>(u, v);

    dim3 gF(CHUNKS, BB);
    for (int it = 0; it < NITER; ++it) {
        k_uv<<<gF, 256, 0, stream>>>(c, v, u, pm, ps);
        k_v_combine<<<(BB * NN) / 64, 256, 0, stream>>>(pm, ps, v);
    }

    unsigned n4 = (unsigned)((size_t)BB * NN * NN / 4);
    k_final<<<n4 / 256, 256, 0, stream>>>(c, u, v, pi, negc);
    k_uv_out<<<(BB * NN) / 256, 256, 0, stream>>>(u, v, ou, ov);
}